// Round 1
// baseline (33.013 us; speedup 1.0000x reference)
//
#include <hip/hip_runtime.h>
#include <hip/hip_bf16.h>

// Problem: B=512, D=128, H=512.
// out[a,b] = W2 . relu( x[a]@W1[0:128] + y[b]@W1[128:256] + b1 ) + b2
// Factored: U[a,h] = x[a]@W1x + b1[h]; V[b,h] = y[b]@W1y;
//           out[a,b] = sum_h relu(U[a,h]+V[b,h]) * W2[h] + b2.

#define B 512
#define D 128
#define H 512
#define CH 64   // h-chunk staged in LDS per iteration of K2

// ---------------- K1: U = x@W1x + b1, V = y@W1y ----------------
// grid (B/4, 2), block 256. blockIdx.y==0 -> U from x, ==1 -> V from y.
// Each thread computes 4 rows x 2 h-values (h = tid, tid+256).
__global__ void k1_uv(const float* __restrict__ x, const float* __restrict__ y,
                      const float* __restrict__ W1, const float* __restrict__ b1,
                      float* __restrict__ U, float* __restrict__ V) {
    const int m  = blockIdx.y;
    const int a0 = blockIdx.x * 4;
    const float* __restrict__ src = (m == 0) ? x : y;
    float* __restrict__ dst       = (m == 0) ? U : V;
    const float* __restrict__ Wm  = W1 + (size_t)m * D * H;

    __shared__ float xs[4][D];
    const int t = threadIdx.x;
    // stage 4 input rows (4*128 floats) into LDS
    for (int i = t; i < 4 * D; i += 256)
        xs[i >> 7][i & (D - 1)] = src[(size_t)(a0 + (i >> 7)) * D + (i & (D - 1))];
    __syncthreads();

    const int h = t;  // h and h+256
    float acc[4][2];
#pragma unroll
    for (int r = 0; r < 4; ++r) {
        acc[r][0] = (m == 0) ? b1[h] : 0.0f;
        acc[r][1] = (m == 0) ? b1[h + 256] : 0.0f;
    }
#pragma unroll 4
    for (int d = 0; d < D; ++d) {
        const float w0 = Wm[(size_t)d * H + h];
        const float w1 = Wm[(size_t)d * H + h + 256];
#pragma unroll
        for (int r = 0; r < 4; ++r) {
            const float xv = xs[r][d];
            acc[r][0] = fmaf(xv, w0, acc[r][0]);
            acc[r][1] = fmaf(xv, w1, acc[r][1]);
        }
    }
#pragma unroll
    for (int r = 0; r < 4; ++r) {
        dst[(size_t)(a0 + r) * H + h]       = acc[r][0];
        dst[(size_t)(a0 + r) * H + h + 256] = acc[r][1];
    }
}

// ---------------- K2: partial[z][a,b] = sum_{h in slice z} relu(U+V)*W2 -----
// grid (8, 8, S), block 256. 64x64 output tile per block; each thread 4x4.
__global__ void k2_pair(const float* __restrict__ U, const float* __restrict__ V,
                        const float* __restrict__ W2, float* __restrict__ P,
                        int hcount) {
    __shared__ float Us[CH][64];
    __shared__ float Vs[CH][64];
    __shared__ float w2s[CH];

    const int a0 = blockIdx.x * 64;
    const int b0 = blockIdx.y * 64;
    const int h0 = blockIdx.z * hcount;
    const int tid = threadIdx.x;
    const int ta = tid & 15;   // a-quad
    const int tb = tid >> 4;   // b-quad

    float acc[4][4] = {};

    const int r = tid >> 2;    // row (a or b index within tile), 0..63
    const int q = tid & 3;     // h-quad within 16

    for (int c = 0; c < hcount; c += CH) {
        const float* __restrict__ Urow = U + (size_t)(a0 + r) * H + h0 + c;
        const float* __restrict__ Vrow = V + (size_t)(b0 + r) * H + h0 + c;
#pragma unroll
        for (int p = 0; p < 4; ++p) {
            const int hh = 4 * q + 16 * p;
            const float4 u4 = *(const float4*)(Urow + hh);
            const float4 v4 = *(const float4*)(Vrow + hh);
            Us[hh + 0][r] = u4.x; Us[hh + 1][r] = u4.y;
            Us[hh + 2][r] = u4.z; Us[hh + 3][r] = u4.w;
            Vs[hh + 0][r] = v4.x; Vs[hh + 1][r] = v4.y;
            Vs[hh + 2][r] = v4.z; Vs[hh + 3][r] = v4.w;
        }
        if (tid < CH) w2s[tid] = W2[h0 + c + tid];
        __syncthreads();

        for (int h = 0; h < CH; ++h) {
            const float4 ua = *(const float4*)&Us[h][4 * ta];
            const float4 vb = *(const float4*)&Vs[h][4 * tb];
            const float w = w2s[h];
            const float u[4] = {ua.x, ua.y, ua.z, ua.w};
            const float v[4] = {vb.x, vb.y, vb.z, vb.w};
#pragma unroll
            for (int i = 0; i < 4; ++i)
#pragma unroll
                for (int j = 0; j < 4; ++j)
                    acc[i][j] = fmaf(fmaxf(u[i] + v[j], 0.0f), w, acc[i][j]);
        }
        __syncthreads();
    }

    float* __restrict__ out = P + (size_t)blockIdx.z * (B * B);
#pragma unroll
    for (int i = 0; i < 4; ++i) {
        float4 o;
        o.x = acc[i][0]; o.y = acc[i][1]; o.z = acc[i][2]; o.w = acc[i][3];
        *(float4*)(out + (size_t)(a0 + 4 * ta + i) * B + b0 + 4 * tb) = o;
    }
}

// ---------------- K3: out = sum_z partial[z] + b2 ----------------
__global__ void k3_reduce(const float* __restrict__ P, const float* __restrict__ b2,
                          float* __restrict__ out, int S) {
    const int i = blockIdx.x * 256 + threadIdx.x;
    float s = b2[0];
    for (int k = 0; k < S; ++k) s += P[(size_t)k * (B * B) + i];
    out[i] = s;
}

extern "C" void kernel_launch(void* const* d_in, const int* in_sizes, int n_in,
                              void* d_out, int out_size, void* d_ws, size_t ws_size,
                              hipStream_t stream) {
    const float* x  = (const float*)d_in[0];
    const float* y  = (const float*)d_in[1];
    const float* W1 = (const float*)d_in[2];
    const float* b1 = (const float*)d_in[3];
    const float* W2 = (const float*)d_in[4];
    const float* b2 = (const float*)d_in[5];
    float* out = (float*)d_out;

    float* U = (float*)d_ws;            // B*H floats = 1 MB
    float* V = U + (size_t)B * H;       // 1 MB
    float* P = V + (size_t)B * H;       // S MB of partials

    const size_t base = 2ull * B * H * sizeof(float);
    int S = 1;
    if (ws_size >= base + 8ull * B * B * sizeof(float)) S = 8;
    else if (ws_size >= base + 4ull * B * B * sizeof(float)) S = 4;
    else if (ws_size >= base + 2ull * B * B * sizeof(float)) S = 2;

    k1_uv<<<dim3(B / 4, 2), 256, 0, stream>>>(x, y, W1, b1, U, V);
    k2_pair<<<dim3(8, 8, S), 256, 0, stream>>>(U, V, W2, P, H / S);
    k3_reduce<<<dim3((B * B) / 256), 256, 0, stream>>>(P, b2, out, S);
}

// Round 2
// 31.688 us; speedup vs baseline: 1.0418x; 1.0418x over previous
//
#include <hip/hip_runtime.h>
#include <hip/hip_bf16.h>

// Problem: B=512, D=128, H=512.
// out[a,b] = W2 . relu( x[a]@W1x + y[b]@W1y + b1 ) + b2
// Identity: relu(t) = (t + |t|)/2, so with U[a,h]=x[a]@W1x+b1, V[b,h]=y[b]@W1y:
//   out[a,b] = b2 + P[a] + Q[b] + 0.5 * sum_h |U[a,h]+V[b,h]| * W2[h]
// where P[a] = sum_h U[a,h]*W2[h]/2, Q[b] = sum_h V[b,h]*W2[h]/2.
// Pairwise inner body is 2 VALU ops (v_add + v_fma with abs modifier).

#define B 512
#define D 128
#define H 512
#define CH 64      // h-chunk staged in LDS per K2 iteration
#define LDP 68     // padded LDS row stride (floats): 16B-aligned, 2-way banks only

// ---------------- K1: U = x@W1x + b1, V = y@W1y, plus P/Q partials ---------
// grid (B/4, 2, 2), block 256. y: m (0->U from x, 1->V from y); z: h-half.
// Thread computes 4 rows x 1 h (h = z*256 + tid).
__global__ __launch_bounds__(256) void k1_uv(
        const float* __restrict__ x, const float* __restrict__ y,
        const float* __restrict__ W1, const float* __restrict__ b1,
        const float* __restrict__ W2,
        float* __restrict__ U, float* __restrict__ V, float* __restrict__ PQ) {
    const int m  = blockIdx.y;
    const int z  = blockIdx.z;
    const int a0 = blockIdx.x * 4;
    const float* __restrict__ src = (m == 0) ? x : y;
    float* __restrict__ dst       = (m == 0) ? U : V;
    const float* __restrict__ Wm  = W1 + (size_t)m * D * H;

    __shared__ float xs[4][D];
    __shared__ float red[4][4];
    const int t = threadIdx.x;
    for (int i = t; i < 4 * D; i += 256)
        xs[i >> 7][i & (D - 1)] = src[(size_t)(a0 + (i >> 7)) * D + (i & (D - 1))];
    __syncthreads();

    const int h = z * 256 + t;
    float bias = (m == 0) ? b1[h] : 0.0f;
    float acc[4] = {bias, bias, bias, bias};
#pragma unroll 4
    for (int d = 0; d < D; ++d) {
        const float w = Wm[(size_t)d * H + h];
#pragma unroll
        for (int r = 0; r < 4; ++r) acc[r] = fmaf(xs[r][d], w, acc[r]);
    }
#pragma unroll
    for (int r = 0; r < 4; ++r) dst[(size_t)(a0 + r) * H + h] = acc[r];

    // P/Q partial for this h-slice: sum_h acc_r * (W2[h]*0.5)
    const float wp = 0.5f * W2[h];
    float v[4];
#pragma unroll
    for (int r = 0; r < 4; ++r) v[r] = acc[r] * wp;
#pragma unroll
    for (int r = 0; r < 4; ++r)
        for (int o = 32; o > 0; o >>= 1) v[r] += __shfl_down(v[r], o);
    const int wave = t >> 6;
    if ((t & 63) == 0)
#pragma unroll
        for (int r = 0; r < 4; ++r) red[wave][r] = v[r];
    __syncthreads();
    if (t < 4) {
        const float s = red[0][t] + red[1][t] + red[2][t] + red[3][t];
        PQ[(size_t)(m * 2 + z) * B + a0 + t] = s;
    }
}

// ---------------- K2: Pz[a,b] = sum_{h in slice z} |U+V| * W2 --------------
// grid (8, 8, S), block 256. 64x64 output tile; each thread 4x4 outputs.
__global__ __launch_bounds__(256) void k2_pair(
        const float* __restrict__ U, const float* __restrict__ V,
        const float* __restrict__ W2, float* __restrict__ P, int hcount) {
    __shared__ float Us[CH][LDP];
    __shared__ float Vs[CH][LDP];

    const int a0 = blockIdx.x * 64;
    const int b0 = blockIdx.y * 64;
    const int h0 = blockIdx.z * hcount;
    const int tid = threadIdx.x;
    const int ta = tid & 15;   // a-quad
    const int tb = tid >> 4;   // b-quad
    const int r = tid >> 2;    // staging row 0..63
    const int q = tid & 3;     // staging h-quad

    float acc[4][4] = {};

    for (int c = 0; c < hcount; c += CH) {
        const float* __restrict__ Urow = U + (size_t)(a0 + r) * H + h0 + c;
        const float* __restrict__ Vrow = V + (size_t)(b0 + r) * H + h0 + c;
#pragma unroll
        for (int p = 0; p < 4; ++p) {
            const int hh = 4 * q + 16 * p;
            const float4 u4 = *(const float4*)(Urow + hh);
            const float4 v4 = *(const float4*)(Vrow + hh);
            Us[hh + 0][r] = u4.x; Us[hh + 1][r] = u4.y;
            Us[hh + 2][r] = u4.z; Us[hh + 3][r] = u4.w;
            Vs[hh + 0][r] = v4.x; Vs[hh + 1][r] = v4.y;
            Vs[hh + 2][r] = v4.z; Vs[hh + 3][r] = v4.w;
        }
        __syncthreads();

#pragma unroll 4
        for (int hh = 0; hh < CH; ++hh) {
            const float w = W2[h0 + c + hh];      // uniform -> scalar load
            const float4 ua = *(const float4*)&Us[hh][4 * ta];
            const float4 vb = *(const float4*)&Vs[hh][4 * tb];
            const float u[4] = {ua.x, ua.y, ua.z, ua.w};
            const float v[4] = {vb.x, vb.y, vb.z, vb.w};
#pragma unroll
            for (int i = 0; i < 4; ++i)
#pragma unroll
                for (int j = 0; j < 4; ++j)
                    acc[i][j] = fmaf(__builtin_fabsf(u[i] + v[j]), w, acc[i][j]);
        }
        __syncthreads();
    }

    float* __restrict__ out = P + (size_t)blockIdx.z * (B * B);
#pragma unroll
    for (int i = 0; i < 4; ++i) {
        float4 o;
        o.x = acc[i][0]; o.y = acc[i][1]; o.z = acc[i][2]; o.w = acc[i][3];
        *(float4*)(out + (size_t)(a0 + 4 * ta + i) * B + b0 + 4 * tb) = o;
    }
}

// ---------------- K3: out = b2 + P[a] + Q[b] + 0.5 * sum_z Pz --------------
// grid (256), block 256; each thread one float4 (4 consecutive b).
__global__ __launch_bounds__(256) void k3_reduce(
        const float* __restrict__ Pp, const float* __restrict__ PQ,
        const float* __restrict__ b2, float* __restrict__ out, int S) {
    const int gi = blockIdx.x * 256 + threadIdx.x;   // float4 index
    const int i = gi * 4;
    const int a = i >> 9;
    const int b = i & (B - 1);

    float4 s = {0.f, 0.f, 0.f, 0.f};
    for (int z = 0; z < S; ++z) {
        const float4 p = *(const float4*)(Pp + (size_t)z * (B * B) + i);
        s.x += p.x; s.y += p.y; s.z += p.z; s.w += p.w;
    }
    const float pa = PQ[a] + PQ[B + a] + b2[0];
    const float4 qb0 = *(const float4*)(PQ + 2 * B + b);
    const float4 qb1 = *(const float4*)(PQ + 3 * B + b);
    float4 o;
    o.x = pa + qb0.x + qb1.x + 0.5f * s.x;
    o.y = pa + qb0.y + qb1.y + 0.5f * s.y;
    o.z = pa + qb0.z + qb1.z + 0.5f * s.z;
    o.w = pa + qb0.w + qb1.w + 0.5f * s.w;
    *(float4*)(out + i) = o;
}

extern "C" void kernel_launch(void* const* d_in, const int* in_sizes, int n_in,
                              void* d_out, int out_size, void* d_ws, size_t ws_size,
                              hipStream_t stream) {
    const float* x  = (const float*)d_in[0];
    const float* y  = (const float*)d_in[1];
    const float* W1 = (const float*)d_in[2];
    const float* b1 = (const float*)d_in[3];
    const float* W2 = (const float*)d_in[4];
    const float* b2 = (const float*)d_in[5];
    float* out = (float*)d_out;

    float* U  = (float*)d_ws;                 // B*H floats = 1 MB
    float* V  = U + (size_t)B * H;            // 1 MB
    float* PQ = V + (size_t)B * H;            // 4*B floats (P halves, Q halves)
    float* Pp = PQ + 4 * B;                   // S * B*B partial planes

    const size_t base = (2ull * B * H + 4 * B) * sizeof(float);
    int S = 1;
    if (ws_size >= base + 8ull * B * B * sizeof(float)) S = 8;
    else if (ws_size >= base + 4ull * B * B * sizeof(float)) S = 4;
    else if (ws_size >= base + 2ull * B * B * sizeof(float)) S = 2;

    k1_uv<<<dim3(B / 4, 2, 2), 256, 0, stream>>>(x, y, W1, b1, W2, U, V, PQ);
    k2_pair<<<dim3(8, 8, S), 256, 0, stream>>>(U, V, W2, Pp, H / S);
    k3_reduce<<<dim3((B * B) / (256 * 4)), 256, 0, stream>>>(Pp, PQ, b2, out, S);
}